// Round 16
// baseline (242.978 us; speedup 1.0000x reference)
//
#include <hip/hip_runtime.h>

#define LL 2048
#define BB 8
#define DD 1024
#define HH 4
#define HD 256

#define AS1 __attribute__((address_space(1)))
#define AS3 __attribute__((address_space(3)))

typedef __attribute__((ext_vector_type(8))) short short8;
typedef __attribute__((ext_vector_type(4))) float f32x4;
typedef unsigned short u16;
typedef unsigned int u32;

static __device__ __forceinline__ u16 f2bf(float f) {
    u32 u = __float_as_uint(f);
    return (u16)((u + 0x7fffu + ((u >> 16) & 1u)) >> 16);
}
static __device__ __forceinline__ float bf2f(u16 v) {
    return __uint_as_float(((u32)v) << 16);
}
static __device__ __forceinline__ float silu2_fast(float x) {
    float s1 = x * __builtin_amdgcn_rcpf(1.0f + __expf(-x));
    return s1 * __builtin_amdgcn_rcpf(1.0f + __expf(-s1));
}

#define BAR_LGKM() do { \
    asm volatile("s_waitcnt lgkmcnt(0)" ::: "memory"); \
    __builtin_amdgcn_s_barrier(); \
    __builtin_amdgcn_sched_barrier(0); \
} while (0)

// ---------------- front v2: cvt-x + fused beta | cvt Wk | cvt Wv | qraw(reuse) ----------------
static __device__ __forceinline__ void cvt8_plain(const float* __restrict__ in,
                                                  u16* __restrict__ out, int blk, int n) {
    int i = (blk * 256 + (int)threadIdx.x) * 8;
    if (i >= n) return;
    float4 a = *(const float4*)(in + i);
    float4 b = *(const float4*)(in + i + 4);
    uint4 pk;
    pk.x = (u32)f2bf(a.x) | ((u32)f2bf(a.y) << 16);
    pk.y = (u32)f2bf(a.z) | ((u32)f2bf(a.w) << 16);
    pk.z = (u32)f2bf(b.x) | ((u32)f2bf(b.y) << 16);
    pk.w = (u32)f2bf(b.z) | ((u32)f2bf(b.w) << 16);
    *(uint4*)(out + i) = pk;
}

__global__ __launch_bounds__(256) void front_kernel(
    const float* __restrict__ x, const float* __restrict__ Wk, const float* __restrict__ Wv,
    const float* __restrict__ Wbeta, const float* __restrict__ Wq,
    u16* __restrict__ XB, u16* __restrict__ WKVB, float* __restrict__ BETA,
    u16* __restrict__ RQ)
{
    __shared__ float wsum[4][4];
    const int blk = blockIdx.x;
    const int tid = threadIdx.x;
    if (blk < 8192) {
        // cvt 2 rows of x + fused beta for those rows
        const long base = (long)blk * 2048 + tid * 8;
        float4 a = *(const float4*)(x + base);
        float4 b = *(const float4*)(x + base + 4);
        uint4 pk;
        pk.x = (u32)f2bf(a.x) | ((u32)f2bf(a.y) << 16);
        pk.y = (u32)f2bf(a.z) | ((u32)f2bf(a.w) << 16);
        pk.z = (u32)f2bf(b.x) | ((u32)f2bf(b.y) << 16);
        pk.w = (u32)f2bf(b.z) | ((u32)f2bf(b.w) << 16);
        *(uint4*)(XB + base) = pk;

        const int col = (tid * 8) & 1023;
        float s[4];
#pragma unroll
        for (int h = 0; h < 4; h++) {
            const float* wr = Wbeta + (long)h * DD + col;
            float4 w0 = *(const float4*)wr;
            float4 w1 = *(const float4*)(wr + 4);
            s[h] = a.x * w0.x + a.y * w0.y + a.z * w0.z + a.w * w0.w +
                   b.x * w1.x + b.y * w1.y + b.z * w1.z + b.w * w1.w;
        }
#pragma unroll
        for (int h = 0; h < 4; h++)
#pragma unroll
            for (int m = 1; m < 64; m <<= 1) s[h] += __shfl_xor(s[h], m);
        const int w = tid >> 6, lane = tid & 63;
        if (lane == 0) {
#pragma unroll
            for (int h = 0; h < 4; h++) wsum[w][h] = s[h];
        }
        __syncthreads();
        if (tid < 8) {
            int r = tid >> 2, h = tid & 3;
            float v = wsum[2 * r][h] + wsum[2 * r + 1][h];
            BETA[((long)blk * 2 + r) * HH + h] = 1.0f / (1.0f + __expf(-v));
        }
    } else if (blk < 8704) {
        cvt8_plain(Wk, WKVB, blk - 8192, 1048576);
    } else if (blk < 9216) {
        cvt8_plain(Wv, WKVB + 1048576, blk - 8704, 1048576);
    } else {
        // qraw v2: wave = one n, loop over all 32 m (Wq row loaded once)
        const int w = tid >> 6, lane = tid & 63;
        const int n = (blk - 9216) * 4 + w;
        const float* wr = Wq + (long)n * DD + lane * 16;
        float4 wv_[4];
#pragma unroll
        for (int u = 0; u < 4; u++) wv_[u] = *(const float4*)(wr + u * 4);
#pragma unroll 4
        for (int m = 0; m < 32; m++) {
            const int bb = m >> 2, j = m & 3;
            const float* xr = x + ((long)bb * LL + (LL - 4 + j)) * DD + lane * 16;
            float s = 0.f;
#pragma unroll
            for (int u = 0; u < 4; u++) {
                float4 av = *(const float4*)(xr + u * 4);
                s += av.x * wv_[u].x + av.y * wv_[u].y + av.z * wv_[u].z + av.w * wv_[u].w;
            }
#pragma unroll
            for (int mm = 1; mm < 64; mm <<= 1) s += __shfl_xor(s, mm);
            if (lane == 0) RQ[(long)m * DD + n] = f2bf(s);
        }
    }
}

// ---------------- 256x256 8-phase GEMM with XCD-aware block swizzle (T1) --------------
__global__ __launch_bounds__(512, 1) void gemm_8ph(const u16* __restrict__ A,
                                                   const u16* __restrict__ W,
                                                   u16* __restrict__ C) {
    __shared__ __align__(16) char sm_[131072];
    const int tid = threadIdx.x;
    const int w = tid >> 6, lane = tid & 63, g = lane >> 4, c = lane & 15;
    const int wm_ = w >> 2, wn_ = w & 3;
    const int bid = blockIdx.x;
    const int by = (bid & 7) * 8 + ((bid >> 3) >> 3);
    const int bx = (bid >> 3) & 7;
    const int m0 = by * 256, n0 = bx * 256;
    const int sr = tid >> 3, cb = (tid & 7) * 16;
    const int ssw = (sr & 7) << 4;
    const int sw = (c & 7) << 4;

    f32x4 acc[8][4];
#pragma unroll
    for (int i = 0; i < 8; i++)
#pragma unroll
        for (int j = 0; j < 4; j++) acc[i][j] = (f32x4){0.f, 0.f, 0.f, 0.f};
    short8 afr[4][2];
    short8 bfr[2][2];

#define GL8(gp, lofs) __builtin_amdgcn_global_load_lds((const AS1 void*)(gp), \
        (AS3 void*)((AS3 char*)sm_ + (lofs)), 16, 0, 0)
#define ST_A(kt, half, PB) { \
    const char* gp_ = (const char*)A + ((long)(m0 + (half)*128 + sr) * 1024 + (kt) * 64) * 2 + (cb ^ ssw); \
    GL8(gp_, (PB) + (half)*16384 + tid*16); GL8(gp_ + 131072, (PB) + (half)*16384 + 8192 + tid*16); }
#define ST_B(kt, half, PB) { \
    const char* gp_ = (const char*)W + ((long)(n0 + (half)*128 + sr) * 1024 + (kt) * 64) * 2 + (cb ^ ssw); \
    GL8(gp_, 65536 + (PB) + (half)*16384 + tid*16); GL8(gp_ + 131072, 65536 + (PB) + (half)*16384 + 8192 + tid*16); }
#define LOADA(qm, PB) { \
    const char* ab_ = sm_ + (PB) + wm_ * 16384 + ((qm) * 64 + c) * 128; \
    _Pragma("unroll") for (int mt = 0; mt < 4; mt++) \
        _Pragma("unroll") for (int ks = 0; ks < 2; ks++) \
            afr[mt][ks] = *(const short8*)(ab_ + mt * 2048 + ((ks * 64 + g * 16) ^ sw)); }
#define LOADB(qn, PB) { \
    const char* bb_ = sm_ + 65536 + (PB) + (wn_ >> 1) * 16384 + ((wn_ & 1) * 64 + (qn) * 32 + c) * 128; \
    _Pragma("unroll") for (int nt = 0; nt < 2; nt++) \
        _Pragma("unroll") for (int ks = 0; ks < 2; ks++) \
            bfr[nt][ks] = *(const short8*)(bb_ + nt * 2048 + ((ks * 64 + g * 16) ^ sw)); }
#define MFMAQ(qm, qn) { \
    __builtin_amdgcn_s_barrier(); \
    __builtin_amdgcn_s_setprio(1); \
    _Pragma("unroll") for (int mt = 0; mt < 4; mt++) \
        _Pragma("unroll") for (int nt = 0; nt < 2; nt++) \
            _Pragma("unroll") for (int ks = 0; ks < 2; ks++) \
                acc[(qm)*4+mt][(qn)*2+nt] = __builtin_amdgcn_mfma_f32_16x16x32_bf16( \
                    afr[mt][ks], bfr[nt][ks], acc[(qm)*4+mt][(qn)*2+nt], 0, 0, 0); \
    __builtin_amdgcn_s_setprio(0); }
#define ENDB() { __builtin_amdgcn_s_barrier(); __builtin_amdgcn_sched_barrier(0); }

    ST_A(0, 0, 0) ST_A(0, 1, 0) ST_B(0, 0, 0) ST_B(0, 1, 0) ST_A(1, 0, 32768)
    asm volatile("s_waitcnt vmcnt(2)" ::: "memory");
    __builtin_amdgcn_s_barrier();
    __builtin_amdgcn_sched_barrier(0);

    for (int u = 0; u < 8; ++u) {
        const int t1k = 2 * u + 1, nk = 2 * u + 2, nk1 = 2 * u + 3;
        const bool more = (u < 7);
        LOADA(0, 0) LOADB(0, 0) ST_A(t1k, 1, 32768) MFMAQ(0, 0) ENDB()
        LOADB(1, 0) ST_B(t1k, 0, 32768) MFMAQ(0, 1) ENDB()
        LOADA(1, 0) LOADB(0, 0) ST_B(t1k, 1, 32768) MFMAQ(1, 0) ENDB()
        LOADB(1, 0)
        if (more) ST_A(nk, 0, 0)
        MFMAQ(1, 1)
        if (more) { asm volatile("s_waitcnt vmcnt(2)" ::: "memory"); }
        else      { asm volatile("s_waitcnt vmcnt(0)" ::: "memory"); }
        ENDB()
        LOADA(0, 32768) LOADB(0, 32768)
        if (more) ST_B(nk, 0, 0)
        MFMAQ(0, 0) ENDB()
        LOADB(1, 32768)
        if (more) ST_A(nk, 1, 0)
        MFMAQ(0, 1) ENDB()
        LOADA(1, 32768) LOADB(0, 32768)
        if (more) ST_B(nk, 1, 0)
        MFMAQ(1, 0) ENDB()
        LOADB(1, 32768)
        if (more) ST_A(nk1, 0, 32768)
        MFMAQ(1, 1)
        if (more) { asm volatile("s_waitcnt vmcnt(2)" ::: "memory"); }
        ENDB()
    }

#pragma unroll
    for (int mt = 0; mt < 8; mt++)
#pragma unroll
        for (int nt = 0; nt < 4; nt++)
#pragma unroll
            for (int r = 0; r < 4; r++)
                C[(long)(m0 + wm_ * 128 + mt * 16 + 4 * g + r) * 2048 +
                  n0 + wn_ * 64 + nt * 16 + c] = f2bf(acc[mt][nt][r]);
#undef GL8
#undef ST_A
#undef ST_B
#undef LOADA
#undef LOADB
#undef MFMAQ
#undef ENDB
}

// ---------------- prep_fused v2: half-width Y (49.5 KB LDS, 3 blocks/CU) ----------------
__global__ __launch_bounds__(256, 3) void prep_fused(
    const u16* __restrict__ R, const float* __restrict__ ck, const float* __restrict__ cv,
    const float* __restrict__ cq, const u16* __restrict__ RQ, const float* __restrict__ BETA,
    u16* __restrict__ LK_g, u16* __restrict__ BKT_g, u16* __restrict__ LV_g,
    u16* __restrict__ QN)
{
    __shared__ __align__(16) char pm[50688];
    const int blk = blockIdx.x;
    const int tid = threadIdx.x;

    if (blk >= 1024) {      // ---- q tail conv (l = 3 over RQ rows b*4..b*4+3) ----
        const int b = blk - 1024;
        const int d = tid * 4;
        float w0[4], w1[4], w2[4], w3[4];
        const float4* cw4 = (const float4*)cq;
        *(float4*)w0 = cw4[d + 0];
        *(float4*)w1 = cw4[d + 1];
        *(float4*)w2 = cw4[d + 2];
        *(float4*)w3 = cw4[d + 3];
        const u16* base = RQ + (long)b * 4 * DD + d;
        float a0 = 0.f, a1 = 0.f, a2 = 0.f, a3 = 0.f;
#pragma unroll
        for (int j = 0; j < 4; j++) {
            uint2 v = *(const uint2*)(base + (long)j * DD);
            a0 += bf2f((u16)(v.x & 0xffff)) * w0[j];
            a1 += bf2f((u16)(v.x >> 16)) * w1[j];
            a2 += bf2f((u16)(v.y & 0xffff)) * w2[j];
            a3 += bf2f((u16)(v.y >> 16)) * w3[j];
        }
        float y0 = silu2_fast(a0);
        float y1 = silu2_fast(a1);
        float y2 = silu2_fast(a2);
        float y3 = silu2_fast(a3);
        float ss = y0 * y0 + y1 * y1 + y2 * y2 + y3 * y3;
#pragma unroll
        for (int m = 1; m < 64; m <<= 1) ss += __shfl_xor(ss, m);
        float sc = 1.0f / fmaxf(sqrtf(ss), 1e-12f);
        y0 *= sc; y1 *= sc; y2 *= sc; y3 *= sc;
        uint2 o;
        o.x = (u32)f2bf(y0) | ((u32)f2bf(y1) << 16);
        o.y = (u32)f2bf(y2) | ((u32)f2bf(y3) << 16);
        *(uint2*)(QN + ((long)b * 4 + 3) * DD + d) = o;
        return;
    }

    const int bh = blk >> 5, q = blk & 31;
    const int b = bh >> 2, h = bh & 3;
    const int w = tid >> 6, lane = tid & 63, g = lane >> 4, c = lane & 15;
    const long cb = (long)(bh * 32 + q);
    u16* WLp = (u16*)(pm + 32768);
    float* bv   = (float*)(pm + 49664);
    float* n2   = (float*)(pm + 49920);
    float* invn = (float*)(pm + 50176);
    float* ncl  = (float*)(pm + 50432);

    if (tid < 64) bv[tid] = BETA[((long)b * LL + 64 * q + tid) * HH + h];

    // ---- P0/P1: k-conv + KK^T in two d-half passes ----
    f32x4 aacc[4];
#pragma unroll
    for (int nt = 0; nt < 4; nt++) aacc[nt] = (f32x4){0.f, 0.f, 0.f, 0.f};

    const int dloc = tid & 127, th = tid >> 7;
#pragma unroll
    for (int pass = 0; pass < 2; pass++) {
        {
            const int dg = pass * 128 + dloc;
            float4 wt = ((const float4*)ck)[h * HD + dg];
            const u16* rp = R + ((long)b * LL + 64 * q) * 2048 + h * HD + dg;
            u16 arr[35];
            if (q == 0 && th == 0) {
                arr[0] = 0; arr[1] = 0; arr[2] = 0;
#pragma unroll
                for (int i = 3; i < 35; i++) arr[i] = rp[(long)(i - 3) * 2048];
            } else {
                const u16* rb = rp + (long)(32 * th - 3) * 2048;
#pragma unroll
                for (int i = 0; i < 35; i++) arr[i] = rb[(long)i * 2048];
            }
            u16 vals[8];
#pragma unroll
            for (int jj = 0; jj < 32; jj++) {
                int t = 32 * th + jj;
                float y = bf2f(arr[jj]) * wt.x + bf2f(arr[jj + 1]) * wt.y +
                          bf2f(arr[jj + 2]) * wt.z + bf2f(arr[jj + 3]) * wt.w;
                y = silu2_fast(y);
                u16 yb = f2bf(y);
                vals[t & 7] = yb;
                *(u16*)(pm + 32768 + t * 256 + ((((dloc >> 3) ^ (t & 7)) << 4) + (dloc & 7) * 2)) = yb;
                if ((t & 7) == 7)
                    *(uint4*)(pm + dg * 128 + (((t >> 3) ^ (dg & 7)) << 4)) = *(uint4*)vals;
            }
        }
        BAR_LGKM();
        {
            const int ra = 16 * w + c;
#pragma unroll
            for (int q8 = 0; q8 < 4; q8++) {
                short8 af = *(const short8*)(pm + 32768 + ra * 256 + (((4 * q8 + g) ^ (ra & 7)) << 4));
#pragma unroll
                for (int nt = 0; nt < 4; nt++) {
                    const int rb = 16 * nt + c;
                    short8 bf = *(const short8*)(pm + 32768 + rb * 256 + (((4 * q8 + g) ^ (rb & 7)) << 4));
                    aacc[nt] = __builtin_amdgcn_mfma_f32_16x16x32_bf16(af, bf, aacc[nt], 0, 0, 0);
                }
            }
        }
        BAR_LGKM();
    }

    // diag -> n2 -> ncl/invn
#pragma unroll
    for (int nt = 0; nt < 4; nt++)
        if (nt == w && (c >> 2) == g) n2[16 * w + c] = aacc[nt][c & 3];
    BAR_LGKM();
    if (tid < 64) {
        float nn = fmaxf(sqrtf(n2[tid]), 1e-12f);
        ncl[tid] = nn;
        invn[tid] = 1.0f / nn;
    }
    BAR_LGKM();

    // WL = A*b*invn_t*invn_s ; BKT out
    {
#pragma unroll
        for (int nt = 0; nt < 4; nt++)
#pragma unroll
            for (int r = 0; r < 4; r++) {
                int tt = 16 * w + 4 * g + r, s = 16 * nt + c;
                WLp[tt * 68 + s] = f2bf(aacc[nt][r] * bv[s] * invn[tt] * invn[s]);
            }
        for (int ii = tid; ii < 2048; ii += 256) {
            int dd = ii >> 3, bl = ii & 7;
            u16 vals[8];
            *(uint4*)vals = *(const uint4*)(pm + dd * 128 + bl * 16);
            int t0 = (bl ^ (dd & 7)) << 3;
#pragma unroll
            for (int j = 0; j < 8; j++)
                vals[j] = f2bf(bf2f(vals[j]) * bv[t0 + j] * invn[t0 + j]);
            *(uint4*)((char*)(BKT_g + cb * 16384) + dd * 128 + bl * 16) = *(uint4*)vals;
        }
    }
    BAR_LGKM();

    // ---- P2: register forward substitution ; LIbf = Linv[t][s]*invn[s] ----
    {
        const int col = 16 * w + c;
        const float sc_col = invn[col];
        float li[16];
#pragma unroll
        for (int u = 0; u < 16; u++) li[u] = (4 * u + g == col) ? 1.0f : 0.0f;
#pragma unroll
        for (int t = 1; t < 64; t++) {
            float acc = 0.f;
#pragma unroll
            for (int u = 0; u <= (t - 1) / 4; u++) {
                int s = 4 * u + g;
                if (s < t) acc += bf2f(WLp[t * 68 + s]) * li[u];
            }
            acc += __shfl_xor(acc, 16);
            acc += __shfl_xor(acc, 32);
            float val = ((t == col) ? 1.0f : 0.0f) - acc;
            if ((t & 3) == g) li[t >> 2] = val;
        }
#pragma unroll
        for (int u = 0; u < 16; u++) {
            int s = 4 * u + g;
            *(u16*)(pm + 41472 + s * 128 + ((((col >> 3) ^ (s & 7)) << 4) + (col & 7) * 2)) =
                f2bf(li[u] * sc_col);
        }
    }
    BAR_LGKM();

    // ---- P3: LK' = -Linv*K_norm, direct global stores ----
    {
        f32x4 lk[4][4];
#pragma unroll
        for (int i = 0; i < 4; i++)
#pragma unroll
            for (int j = 0; j < 4; j++) lk[i][j] = (f32x4){0.f, 0.f, 0.f, 0.f};
#pragma unroll
        for (int qs = 0; qs < 2; qs++) {
            short8 aL[4], bK[4];
#pragma unroll
            for (int mt = 0; mt < 4; mt++)
                aL[mt] = *(const short8*)(pm + 41472 + (16 * mt + c) * 128 +
                                          (((qs * 4 + g) ^ (c & 7)) << 4));
#pragma unroll
            for (int dn = 0; dn < 4; dn++)
                bK[dn] = *(const short8*)(pm + (64 * w + 16 * dn + c) * 128 +
                                          (((qs * 4 + g) ^ (c & 7)) << 4));
#pragma unroll
            for (int mt = 0; mt < 4; mt++)
#pragma unroll
                for (int dn = 0; dn < 4; dn++)
                    lk[mt][dn] = __builtin_amdgcn_mfma_f32_16x16x32_bf16(aL[mt], bK[dn], lk[mt][dn], 0, 0, 0);
        }
        char* lkg = (char*)(LK_g + cb * 16384);
#pragma unroll
        for (int mt = 0; mt < 4; mt++)
#pragma unroll
            for (int dn = 0; dn < 4; dn++)
#pragma unroll
                for (int r = 0; r < 4; r++) {
                    int t = 16 * mt + 4 * g + r;
                    int d = 64 * w + 16 * dn + c;
                    *(u16*)(lkg + t * 512 + ((((d >> 3) ^ (t & 7)) << 4) + (d & 7) * 2)) =
                        f2bf(-lk[mt][dn][r]);
                }
    }
    BAR_LGKM();   // KT reads done before VT overwrite

    // ---- P4: v-conv gather -> VT [d][t] scaled by ncl[t] (overwrites KT) ----
    {
        float4 wt = ((const float4*)cv)[h * HD + tid];
        const u16* rp = R + ((long)b * LL + 64 * q) * 2048 + 1024 + h * HD + tid;
#pragma unroll
        for (int hh = 0; hh < 2; hh++) {
            u16 arr[35];
            if (q == 0 && hh == 0) {
                arr[0] = 0; arr[1] = 0; arr[2] = 0;
#pragma unroll
                for (int i = 3; i < 35; i++) arr[i] = rp[(long)(i - 3) * 2048];
            } else {
                const u16* rb = rp + (long)(32 * hh - 3) * 2048;
#pragma unroll
                for (int i = 0; i < 35; i++) arr[i] = rb[(long)i * 2048];
            }
            u16 vals[8];
#pragma unroll
            for (int jj = 0; jj < 32; jj++) {
                int t = 32 * hh + jj;
                float y = bf2f(arr[jj]) * wt.x + bf2f(arr[jj + 1]) * wt.y +
                          bf2f(arr[jj + 2]) * wt.z + bf2f(arr[jj + 3]) * wt.w;
                y = silu2_fast(y) * ncl[t];
                vals[t & 7] = f2bf(y);
                if ((t & 7) == 7)
                    *(uint4*)(pm + tid * 128 + (((t >> 3) ^ (tid & 7)) << 4)) = *(uint4*)vals;
            }
        }
    }
    BAR_LGKM();

    // ---- P5: LV' = Linv*V, coalesced u32 plane stores ----
    {
        f32x4 lv[4][4];
#pragma unroll
        for (int i = 0; i < 4; i++)
#pragma unroll
            for (int j = 0; j < 4; j++) lv[i][j] = (f32x4){0.f, 0.f, 0.f, 0.f};
#pragma unroll
        for (int qs = 0; qs < 2; qs++) {
            short8 aL[4], bV[4];
#pragma unroll
            for (int mt = 0; mt < 4; mt++)
                aL[mt] = *(const short8*)(pm + 41472 + (16 * mt + c) * 128 +
                                          (((qs * 4 + g) ^ (c & 7)) << 4));
#pragma unroll
            for (int dn = 0; dn < 4; dn++)
                bV[dn] = *(const short8*)(pm + (64 * w + 16 * dn + c) * 128 +
                                          (((qs * 4 + g) ^ (c & 7)) << 4));
#pragma unroll
            for (int mt = 0; mt < 4; mt++)
#pragma unroll
                for (int dn = 0; dn < 4; dn++)
                    lv[mt][dn] = __builtin_amdgcn_mfma_f32_16x16x32_bf16(aL[mt], bV[dn], lv[mt][dn], 0, 0, 0);
        }
        u32* lvg = (u32*)LV_g + cb * 8192;
#pragma unroll
        for (int mt = 0; mt < 4; mt++)
#pragma unroll
            for (int dn = 0; dn < 4; dn++) {
                int iblk = 2 * w + (dn >> 1);
                int it = dn & 1;
                int base = iblk * 1024 + 64 * (2 * mt + it) + 16 * g + c;
                lvg[base]       = (u32)f2bf(lv[mt][dn][0]) | ((u32)f2bf(lv[mt][dn][1]) << 16);
                lvg[base + 512] = (u32)f2bf(lv[mt][dn][2]) | ((u32)f2bf(lv[mt][dn][3]) << 16);
            }
    }
}

// ---------------- scan v3: LK in registers (dbuf), BKT/LV in LDS, 2 barriers/chunk ----
// LDS: BKT dbuf [0,64K) | LV dbuf [64K,72K) | W [72K,76K) | TS [76K,92K)
__global__ __launch_bounds__(512, 1) void scan_chunked(
    const u16* __restrict__ LK_g, const u16* __restrict__ BKT_g,
    const u16* __restrict__ LV_g, const u16* __restrict__ QN,
    float* __restrict__ out, float* __restrict__ ORAW)
{
    __shared__ __align__(16) char smem[94208];
    const int blk = blockIdx.x;
    const int bh = blk & 31, iblk = blk >> 5;
    const int b = bh >> 2, h = bh & 3;
    const int row0 = iblk * 32;
    const int tid = threadIdx.x;
    const int w = tid >> 6, lane = tid & 63, g = lane >> 4, c = lane & 15;
    const int mt = w >> 1, it = w & 1;
    const int sw = (c & 7) << 4;

#define GLDS16(gp, lofs) __builtin_amdgcn_global_load_lds((const AS1 void*)(gp), \
        (AS3 void*)((AS3 char*)smem + (lofs)), 16, 0, 0)
#define GLDS4(gp, lofs) __builtin_amdgcn_global_load_lds((const AS1 void*)(gp), \
        (AS3 void*)((AS3 char*)smem + (lofs)), 4, 0, 0)
#define STAGE_BKT(qq, bi) { const char* gp = (const char*)(BKT_g + (long)(bh * 32 + (qq)) * 16384); \
    _Pragma("unroll") for (int i_ = 0; i_ < 4; i_++) GLDS16(gp + i_ * 8192 + tid * 16, (bi) * 32768 + i_ * 8192 + tid * 16); }
#define STAGE_LV(qq, bi) { const char* gp = (const char*)LV_g + (long)(bh * 32 + (qq)) * 32768 + iblk * 4096; \
    GLDS4(gp + tid * 4, 65536 + (bi) * 4096 + tid * 4); \
    GLDS4(gp + 2048 + tid * 4, 65536 + (bi) * 4096 + 2048 + tid * 4); }
// LK fragment loads: global image == old linear LDS image, so same offsets read directly.
#define LKLOAD(dst, qq) { \
    const char* base_ = (const char*)LK_g + (long)(bh * 32 + (qq)) * 32768 + (16 * mt + c) * 512; \
    _Pragma("unroll") for (int q8 = 0; q8 < 8; q8++) \
        dst[q8] = *(const short8*)(base_ + (((q8 * 4 + g) << 4) ^ sw)); }

    f32x4 S[2][2];
#pragma unroll
    for (int si = 0; si < 2; si++)
#pragma unroll
        for (int sj = 0; sj < 2; sj++) S[si][sj] = (f32x4){0.f, 0.f, 0.f, 0.f};

    short8 lkA[8], lkB[8];

    // prologue: chunk-0 operands staged + landed before the loop
    LKLOAD(lkA, 0)
    STAGE_BKT(0, 0); STAGE_LV(0, 0);
    asm volatile("s_waitcnt vmcnt(0)" ::: "memory");
    __builtin_amdgcn_s_barrier();
    __builtin_amdgcn_sched_barrier(0);

#define BODY(q, LKC, LKN)                                                                 \
    {                                                                                     \
        const int cur = (q) & 1;                                                          \
        if ((q) < 31) { LKLOAD(LKN, (q) + 1) STAGE_BKT((q) + 1, cur ^ 1); STAGE_LV((q) + 1, cur ^ 1); } \
        const char* bkb = smem + cur * 32768;                                             \
        const char* lvb = smem + 65536 + cur * 4096;                                      \
        u32 l0 = *(const u32*)(lvb + tid * 4);                                            \
        u32 l1 = *(const u32*)(lvb + 2048 + tid * 4);                                     \
        f32x4 w0, w1;                                                                     \
        w0[0] = bf2f((u16)(l0 & 0xffff)); w0[1] = bf2f((u16)(l0 >> 16));                  \
        w0[2] = bf2f((u16)(l1 & 0xffff)); w0[3] = bf2f((u16)(l1 >> 16));                  \
        w1 = (f32x4){0.f, 0.f, 0.f, 0.f};                                                 \
        if ((q) > 0) {                                                                    \
            const int brow = (16 * it + c) * 512;                                         \
            __builtin_amdgcn_s_setprio(1);                                                \
            _Pragma("unroll")                                                             \
            for (int q8 = 0; q8 < 8; q8++) {                                              \
                short8 bv8 = *(const short8*)(smem + 77824 + brow + (((q8 * 4 + g) << 4) ^ sw)); \
                if (q8 & 1) w1 = __builtin_amdgcn_mfma_f32_16x16x32_bf16(LKC[q8], bv8, w1, 0, 0, 0); \
                else        w0 = __builtin_amdgcn_mfma_f32_16x16x32_bf16(LKC[q8], bv8, w0, 0, 0, 0); \
            }                                                                             \
            __builtin_amdgcn_s_setprio(0);                                                \
            _Pragma("unroll")                                                             \
            for (int r = 0; r < 4; r++) w0[r] += w1[r];                                   \
        }                                                                                 \
        {                                                                                 \
            char* ub = smem + 73728 + (16 * it + c) * 128;                                \
            _Pragma("unroll")                                                             \
            for (int r = 0; r < 4; r++) {                                                 \
                int t = 16 * mt + 4 * g + r;                                              \
                *(u16*)(ub + ((((t >> 3) << 4) ^ sw) + (t & 7) * 2)) = f2bf(w0[r]);       \
            }                                                                             \
        }                                                                                 \
        asm volatile("s_waitcnt lgkmcnt(0)" ::: "memory");                                \
        __builtin_amdgcn_s_barrier();                                                     \
        __builtin_amdgcn_sched_barrier(0);                                                \
        __builtin_amdgcn_s_setprio(1);                                                    \
        _Pragma("unroll")                                                                 \
        for (int Qp = 0; Qp < 2; Qp++) {                                                  \
            const int tof = ((Qp * 4 + g) << 4) ^ sw;                                     \
            short8 a0 = *(const short8*)(smem + 73728 + c * 128 + tof);                   \
            short8 a1 = *(const short8*)(smem + 73728 + (16 + c) * 128 + tof);            \
            short8 b0 = *(const short8*)(bkb + (32 * w + c) * 128 + tof);                 \
            short8 b1 = *(const short8*)(bkb + (32 * w + 16 + c) * 128 + tof);            \
            S[0][0] = __builtin_amdgcn_mfma_f32_16x16x32_bf16(a0, b0, S[0][0], 0, 0, 0);  \
            S[0][1] = __builtin_amdgcn_mfma_f32_16x16x32_bf16(a0, b1, S[0][1], 0, 0, 0);  \
            S[1][0] = __builtin_amdgcn_mfma_f32_16x16x32_bf16(a1, b0, S[1][0], 0, 0, 0);  \
            S[1][1] = __builtin_amdgcn_mfma_f32_16x16x32_bf16(a1, b1, S[1][1], 0, 0, 0);  \
        }                                                                                 \
        __builtin_amdgcn_s_setprio(0);                                                    \
        if ((q) < 31) {                                                                   \
            _Pragma("unroll")                                                             \
            for (int si = 0; si < 2; si++)                                                \
                _Pragma("unroll")                                                         \
                for (int sj = 0; sj < 2; sj++)                                            \
                    _Pragma("unroll")                                                     \
                    for (int r = 0; r < 4; r++) {                                         \
                        int i = 16 * si + 4 * g + r;                                      \
                        *(u16*)(smem + 77824 + i * 512 +                                  \
                                ((((4 * w + 2 * sj + (c >> 3)) << 4) ^ ((i & 7) << 4)) + (c & 7) * 2)) = \
                            f2bf(S[si][sj][r]);                                           \
                    }                                                                     \
        }                                                                                 \
        asm volatile("s_waitcnt vmcnt(0) lgkmcnt(0)" ::: "memory");                       \
        __builtin_amdgcn_s_barrier();                                                     \
        __builtin_amdgcn_sched_barrier(0);                                                \
    }

#pragma unroll 1
    for (int qq = 0; qq < 16; ++qq) {
        BODY(2 * qq, lkA, lkB)
        BODY(2 * qq + 1, lkB, lkA)
    }

    // ---- epilogue ----
    float op[2][4];
#pragma unroll
    for (int si = 0; si < 2; si++)
#pragma unroll
        for (int r = 0; r < 4; r++) op[si][r] = 0.f;
#pragma unroll
    for (int sj = 0; sj < 2; sj++) {
        const float qv = bf2f(QN[((long)b * 4 + 3) * DD + h * HD + 32 * w + 16 * sj + c]);
#pragma unroll
        for (int si = 0; si < 2; si++)
#pragma unroll
            for (int r = 0; r < 4; r++) op[si][r] += S[si][sj][r] * qv;
    }
#pragma unroll
    for (int si = 0; si < 2; si++)
#pragma unroll
        for (int r = 0; r < 4; r++) {
            float v = op[si][r];
            v += __shfl_xor(v, 1); v += __shfl_xor(v, 2);
            v += __shfl_xor(v, 4); v += __shfl_xor(v, 8);
            op[si][r] = v;
        }
    float* red = (float*)smem;
    if (c == 0) {
#pragma unroll
        for (int si = 0; si < 2; si++)
#pragma unroll
            for (int r = 0; r < 4; r++) red[w * 32 + 16 * si + 4 * g + r] = op[si][r];
    }
    __syncthreads();
    if (tid < 32) {
        float o = 0.f;
#pragma unroll
        for (int ww = 0; ww < 8; ww++) o += red[ww * 32 + tid];
        ORAW[(long)b * DD + h * HD + row0 + tid] = o;
    }
#pragma unroll
    for (int si = 0; si < 2; si++)
#pragma unroll
        for (int sj = 0; sj < 2; sj++)
#pragma unroll
            for (int r = 0; r < 4; r++)
                out[8192 + ((long)(bh * 256 + row0 + 16 * si + 4 * g + r)) * 256
                    + 32 * w + 16 * sj + c] = S[si][sj][r];
#undef GLDS16
#undef GLDS4
#undef STAGE_BKT
#undef STAGE_LV
#undef LKLOAD
#undef BODY
}

// ---------------- tail: rmsnorm + out projection fused ----------------
__global__ __launch_bounds__(256) void tail_kernel(const float* __restrict__ ORAW,
                                                   const float* __restrict__ rms_w,
                                                   const float* __restrict__ Wout,
                                                   float* __restrict__ out) {
    const int b = blockIdx.x >> 8;
    const int n = (blockIdx.x & 255) * 4 + (threadIdx.x >> 6);
    const int lane = threadIdx.x & 63;
    const int t = threadIdx.x;

    float4 v = *(const float4*)(ORAW + (long)b * DD + t * 4);
    float ss = v.x * v.x + v.y * v.y + v.z * v.z + v.w * v.w;
#pragma unroll
    for (int m = 1; m < 64; m <<= 1) ss += __shfl_xor(ss, m);
    __shared__ float wsum[4];
    if ((t & 63) == 0) wsum[t >> 6] = ss;
    __syncthreads();
    float tot = wsum[0] + wsum[1] + wsum[2] + wsum[3];
    float sc = rsqrtf(tot / (float)DD + 1e-5f);

    const float* orow = ORAW + (long)b * DD + lane * 16;
    const float* grow = rms_w + lane * 16;
    const float* wrow = Wout + (long)n * DD + lane * 16;
    float s = 0.f;
#pragma unroll
    for (int u = 0; u < 4; u++) {
        float4 a = *(const float4*)(orow + u * 4);
        float4 gw = *(const float4*)(grow + u * 4);
        float4 ww = *(const float4*)(wrow + u * 4);
        s += a.x * sc * gw.x * ww.x + a.y * sc * gw.y * ww.y +
             a.z * sc * gw.z * ww.z + a.w * sc * gw.w * ww.w;
    }
#pragma unroll
    for (int m = 1; m < 64; m <<= 1) s += __shfl_xor(s, m);
    if (lane == 0) out[(long)b * DD + n] = s;
}

extern "C" void kernel_launch(void* const* d_in, const int* in_sizes, int n_in,
                              void* d_out, int out_size, void* d_ws, size_t ws_size,
                              hipStream_t stream) {
    const float* x     = (const float*)d_in[0];
    const float* Wq    = (const float*)d_in[1];
    const float* Wk    = (const float*)d_in[2];
    const float* Wv    = (const float*)d_in[3];
    const float* cq    = (const float*)d_in[4];
    const float* ck    = (const float*)d_in[5];
    const float* cv    = (const float*)d_in[6];
    const float* Wbeta = (const float*)d_in[7];
    const float* rms_w = (const float*)d_in[8];
    const float* Wout  = (const float*)d_in[9];
    float* out = (float*)d_out;

    char* ws = (char*)d_ws;
    u16* XB     = (u16*)(ws + 0);           // 32 MB (dead after gemm)
    u16* BKT_g  = (u16*)(ws + 0);           // overlays XB (prep runs after gemm)
    u16* WKVB   = (u16*)(ws + 33554432);    // 4 MB [Wk;Wv]
    u16* R      = (u16*)(ws + 37748736);    // 64 MB [16384][2048] (alive through prep)
    u16* LK_g   = (u16*)(ws + 104857600);   // 32 MB
    u16* LV_g   = (u16*)(ws + 138412032);   // 32 MB
    float* BETA = (float*)(ws + 171966464); // 256 KB
    u16* RQ     = (u16*)(ws + 172228608);   // 64 KB
    u16* QN     = (u16*)(ws + 172294144);   // 64 KB
    float* ORAW = (float*)(ws + 172359680); // 32 KB

    front_kernel<<<9472, 256, 0, stream>>>(x, Wk, Wv, Wbeta, Wq, XB, WKVB, BETA, RQ);
    gemm_8ph<<<512, 512, 0, stream>>>(XB, WKVB, R);
    prep_fused<<<1032, 256, 0, stream>>>(R, ck, cv, cq, RQ, BETA, LK_g, BKT_g, LV_g, QN);
    scan_chunked<<<256, 512, 0, stream>>>(LK_g, BKT_g, LV_g, QN, out, ORAW);
    tail_kernel<<<2048, 256, 0, stream>>>(ORAW, rms_w, Wout, out);
}

// Round 17
// 234.995 us; speedup vs baseline: 1.0340x; 1.0340x over previous
//
#include <hip/hip_runtime.h>

#define LL 2048
#define BB 8
#define DD 1024
#define HH 4
#define HD 256

#define AS1 __attribute__((address_space(1)))
#define AS3 __attribute__((address_space(3)))

typedef __attribute__((ext_vector_type(8))) short short8;
typedef __attribute__((ext_vector_type(4))) float f32x4;
typedef unsigned short u16;
typedef unsigned int u32;

static __device__ __forceinline__ u16 f2bf(float f) {
    u32 u = __float_as_uint(f);
    return (u16)((u + 0x7fffu + ((u >> 16) & 1u)) >> 16);
}
static __device__ __forceinline__ float bf2f(u16 v) {
    return __uint_as_float(((u32)v) << 16);
}
static __device__ __forceinline__ float silu2_fast(float x) {
    float s1 = x * __builtin_amdgcn_rcpf(1.0f + __expf(-x));
    return s1 * __builtin_amdgcn_rcpf(1.0f + __expf(-s1));
}

#define BAR_LGKM() do { \
    asm volatile("s_waitcnt lgkmcnt(0)" ::: "memory"); \
    __builtin_amdgcn_s_barrier(); \
    __builtin_amdgcn_sched_barrier(0); \
} while (0)

// ---------------- front v2: cvt-x + fused beta | cvt Wk | cvt Wv | qraw(reuse) ----------------
static __device__ __forceinline__ void cvt8_plain(const float* __restrict__ in,
                                                  u16* __restrict__ out, int blk, int n) {
    int i = (blk * 256 + (int)threadIdx.x) * 8;
    if (i >= n) return;
    float4 a = *(const float4*)(in + i);
    float4 b = *(const float4*)(in + i + 4);
    uint4 pk;
    pk.x = (u32)f2bf(a.x) | ((u32)f2bf(a.y) << 16);
    pk.y = (u32)f2bf(a.z) | ((u32)f2bf(a.w) << 16);
    pk.z = (u32)f2bf(b.x) | ((u32)f2bf(b.y) << 16);
    pk.w = (u32)f2bf(b.z) | ((u32)f2bf(b.w) << 16);
    *(uint4*)(out + i) = pk;
}

__global__ __launch_bounds__(256) void front_kernel(
    const float* __restrict__ x, const float* __restrict__ Wk, const float* __restrict__ Wv,
    const float* __restrict__ Wbeta, const float* __restrict__ Wq,
    u16* __restrict__ XB, u16* __restrict__ WKVB, float* __restrict__ BETA,
    u16* __restrict__ RQ)
{
    __shared__ float wsum[4][4];
    const int blk = blockIdx.x;
    const int tid = threadIdx.x;
    if (blk < 8192) {
        // cvt 2 rows of x + fused beta for those rows
        const long base = (long)blk * 2048 + tid * 8;
        float4 a = *(const float4*)(x + base);
        float4 b = *(const float4*)(x + base + 4);
        uint4 pk;
        pk.x = (u32)f2bf(a.x) | ((u32)f2bf(a.y) << 16);
        pk.y = (u32)f2bf(a.z) | ((u32)f2bf(a.w) << 16);
        pk.z = (u32)f2bf(b.x) | ((u32)f2bf(b.y) << 16);
        pk.w = (u32)f2bf(b.z) | ((u32)f2bf(b.w) << 16);
        *(uint4*)(XB + base) = pk;

        const int col = (tid * 8) & 1023;
        float s[4];
#pragma unroll
        for (int h = 0; h < 4; h++) {
            const float* wr = Wbeta + (long)h * DD + col;
            float4 w0 = *(const float4*)wr;
            float4 w1 = *(const float4*)(wr + 4);
            s[h] = a.x * w0.x + a.y * w0.y + a.z * w0.z + a.w * w0.w +
                   b.x * w1.x + b.y * w1.y + b.z * w1.z + b.w * w1.w;
        }
#pragma unroll
        for (int h = 0; h < 4; h++)
#pragma unroll
            for (int m = 1; m < 64; m <<= 1) s[h] += __shfl_xor(s[h], m);
        const int w = tid >> 6, lane = tid & 63;
        if (lane == 0) {
#pragma unroll
            for (int h = 0; h < 4; h++) wsum[w][h] = s[h];
        }
        __syncthreads();
        if (tid < 8) {
            int r = tid >> 2, h = tid & 3;
            float v = wsum[2 * r][h] + wsum[2 * r + 1][h];
            BETA[((long)blk * 2 + r) * HH + h] = 1.0f / (1.0f + __expf(-v));
        }
    } else if (blk < 8704) {
        cvt8_plain(Wk, WKVB, blk - 8192, 1048576);
    } else if (blk < 9216) {
        cvt8_plain(Wv, WKVB + 1048576, blk - 8704, 1048576);
    } else {
        // qraw v2: wave = one n, loop over all 32 m (Wq row loaded once)
        const int w = tid >> 6, lane = tid & 63;
        const int n = (blk - 9216) * 4 + w;
        const float* wr = Wq + (long)n * DD + lane * 16;
        float4 wv_[4];
#pragma unroll
        for (int u = 0; u < 4; u++) wv_[u] = *(const float4*)(wr + u * 4);
#pragma unroll 4
        for (int m = 0; m < 32; m++) {
            const int bb = m >> 2, j = m & 3;
            const float* xr = x + ((long)bb * LL + (LL - 4 + j)) * DD + lane * 16;
            float s = 0.f;
#pragma unroll
            for (int u = 0; u < 4; u++) {
                float4 av = *(const float4*)(xr + u * 4);
                s += av.x * wv_[u].x + av.y * wv_[u].y + av.z * wv_[u].z + av.w * wv_[u].w;
            }
#pragma unroll
            for (int mm = 1; mm < 64; mm <<= 1) s += __shfl_xor(s, mm);
            if (lane == 0) RQ[(long)m * DD + n] = f2bf(s);
        }
    }
}

// ---------------- 256x256 8-phase GEMM with XCD-aware block swizzle (T1) --------------
__global__ __launch_bounds__(512, 1) void gemm_8ph(const u16* __restrict__ A,
                                                   const u16* __restrict__ W,
                                                   u16* __restrict__ C) {
    __shared__ __align__(16) char sm_[131072];
    const int tid = threadIdx.x;
    const int w = tid >> 6, lane = tid & 63, g = lane >> 4, c = lane & 15;
    const int wm_ = w >> 2, wn_ = w & 3;
    const int bid = blockIdx.x;
    const int by = (bid & 7) * 8 + ((bid >> 3) >> 3);
    const int bx = (bid >> 3) & 7;
    const int m0 = by * 256, n0 = bx * 256;
    const int sr = tid >> 3, cb = (tid & 7) * 16;
    const int ssw = (sr & 7) << 4;
    const int sw = (c & 7) << 4;

    f32x4 acc[8][4];
#pragma unroll
    for (int i = 0; i < 8; i++)
#pragma unroll
        for (int j = 0; j < 4; j++) acc[i][j] = (f32x4){0.f, 0.f, 0.f, 0.f};
    short8 afr[4][2];
    short8 bfr[2][2];

#define GL8(gp, lofs) __builtin_amdgcn_global_load_lds((const AS1 void*)(gp), \
        (AS3 void*)((AS3 char*)sm_ + (lofs)), 16, 0, 0)
#define ST_A(kt, half, PB) { \
    const char* gp_ = (const char*)A + ((long)(m0 + (half)*128 + sr) * 1024 + (kt) * 64) * 2 + (cb ^ ssw); \
    GL8(gp_, (PB) + (half)*16384 + tid*16); GL8(gp_ + 131072, (PB) + (half)*16384 + 8192 + tid*16); }
#define ST_B(kt, half, PB) { \
    const char* gp_ = (const char*)W + ((long)(n0 + (half)*128 + sr) * 1024 + (kt) * 64) * 2 + (cb ^ ssw); \
    GL8(gp_, 65536 + (PB) + (half)*16384 + tid*16); GL8(gp_ + 131072, 65536 + (PB) + (half)*16384 + 8192 + tid*16); }
#define LOADA(qm, PB) { \
    const char* ab_ = sm_ + (PB) + wm_ * 16384 + ((qm) * 64 + c) * 128; \
    _Pragma("unroll") for (int mt = 0; mt < 4; mt++) \
        _Pragma("unroll") for (int ks = 0; ks < 2; ks++) \
            afr[mt][ks] = *(const short8*)(ab_ + mt * 2048 + ((ks * 64 + g * 16) ^ sw)); }
#define LOADB(qn, PB) { \
    const char* bb_ = sm_ + 65536 + (PB) + (wn_ >> 1) * 16384 + ((wn_ & 1) * 64 + (qn) * 32 + c) * 128; \
    _Pragma("unroll") for (int nt = 0; nt < 2; nt++) \
        _Pragma("unroll") for (int ks = 0; ks < 2; ks++) \
            bfr[nt][ks] = *(const short8*)(bb_ + nt * 2048 + ((ks * 64 + g * 16) ^ sw)); }
#define MFMAQ(qm, qn) { \
    __builtin_amdgcn_s_barrier(); \
    __builtin_amdgcn_s_setprio(1); \
    _Pragma("unroll") for (int mt = 0; mt < 4; mt++) \
        _Pragma("unroll") for (int nt = 0; nt < 2; nt++) \
            _Pragma("unroll") for (int ks = 0; ks < 2; ks++) \
                acc[(qm)*4+mt][(qn)*2+nt] = __builtin_amdgcn_mfma_f32_16x16x32_bf16( \
                    afr[mt][ks], bfr[nt][ks], acc[(qm)*4+mt][(qn)*2+nt], 0, 0, 0); \
    __builtin_amdgcn_s_setprio(0); }
#define ENDB() { __builtin_amdgcn_s_barrier(); __builtin_amdgcn_sched_barrier(0); }

    ST_A(0, 0, 0) ST_A(0, 1, 0) ST_B(0, 0, 0) ST_B(0, 1, 0) ST_A(1, 0, 32768)
    asm volatile("s_waitcnt vmcnt(2)" ::: "memory");
    __builtin_amdgcn_s_barrier();
    __builtin_amdgcn_sched_barrier(0);

    for (int u = 0; u < 8; ++u) {
        const int t1k = 2 * u + 1, nk = 2 * u + 2, nk1 = 2 * u + 3;
        const bool more = (u < 7);
        LOADA(0, 0) LOADB(0, 0) ST_A(t1k, 1, 32768) MFMAQ(0, 0) ENDB()
        LOADB(1, 0) ST_B(t1k, 0, 32768) MFMAQ(0, 1) ENDB()
        LOADA(1, 0) LOADB(0, 0) ST_B(t1k, 1, 32768) MFMAQ(1, 0) ENDB()
        LOADB(1, 0)
        if (more) ST_A(nk, 0, 0)
        MFMAQ(1, 1)
        if (more) { asm volatile("s_waitcnt vmcnt(2)" ::: "memory"); }
        else      { asm volatile("s_waitcnt vmcnt(0)" ::: "memory"); }
        ENDB()
        LOADA(0, 32768) LOADB(0, 32768)
        if (more) ST_B(nk, 0, 0)
        MFMAQ(0, 0) ENDB()
        LOADB(1, 32768)
        if (more) ST_A(nk, 1, 0)
        MFMAQ(0, 1) ENDB()
        LOADA(1, 32768) LOADB(0, 32768)
        if (more) ST_B(nk, 1, 0)
        MFMAQ(1, 0) ENDB()
        LOADB(1, 32768)
        if (more) ST_A(nk1, 0, 32768)
        MFMAQ(1, 1)
        if (more) { asm volatile("s_waitcnt vmcnt(2)" ::: "memory"); }
        ENDB()
    }

#pragma unroll
    for (int mt = 0; mt < 8; mt++)
#pragma unroll
        for (int nt = 0; nt < 4; nt++)
#pragma unroll
            for (int r = 0; r < 4; r++)
                C[(long)(m0 + wm_ * 128 + mt * 16 + 4 * g + r) * 2048 +
                  n0 + wn_ * 64 + nt * 16 + c] = f2bf(acc[mt][nt][r]);
#undef GL8
#undef ST_A
#undef ST_B
#undef LOADA
#undef LOADB
#undef MFMAQ
#undef ENDB
}

// ---------------- prep_fused v2: half-width Y (49.5 KB LDS, 3 blocks/CU) ----------------
__global__ __launch_bounds__(256, 3) void prep_fused(
    const u16* __restrict__ R, const float* __restrict__ ck, const float* __restrict__ cv,
    const float* __restrict__ cq, const u16* __restrict__ RQ, const float* __restrict__ BETA,
    u16* __restrict__ LK_g, u16* __restrict__ BKT_g, u16* __restrict__ LV_g,
    u16* __restrict__ QN)
{
    __shared__ __align__(16) char pm[50688];
    const int blk = blockIdx.x;
    const int tid = threadIdx.x;

    if (blk >= 1024) {      // ---- q tail conv (l = 3 over RQ rows b*4..b*4+3) ----
        const int b = blk - 1024;
        const int d = tid * 4;
        float w0[4], w1[4], w2[4], w3[4];
        const float4* cw4 = (const float4*)cq;
        *(float4*)w0 = cw4[d + 0];
        *(float4*)w1 = cw4[d + 1];
        *(float4*)w2 = cw4[d + 2];
        *(float4*)w3 = cw4[d + 3];
        const u16* base = RQ + (long)b * 4 * DD + d;
        float a0 = 0.f, a1 = 0.f, a2 = 0.f, a3 = 0.f;
#pragma unroll
        for (int j = 0; j < 4; j++) {
            uint2 v = *(const uint2*)(base + (long)j * DD);
            a0 += bf2f((u16)(v.x & 0xffff)) * w0[j];
            a1 += bf2f((u16)(v.x >> 16)) * w1[j];
            a2 += bf2f((u16)(v.y & 0xffff)) * w2[j];
            a3 += bf2f((u16)(v.y >> 16)) * w3[j];
        }
        float y0 = silu2_fast(a0);
        float y1 = silu2_fast(a1);
        float y2 = silu2_fast(a2);
        float y3 = silu2_fast(a3);
        float ss = y0 * y0 + y1 * y1 + y2 * y2 + y3 * y3;
#pragma unroll
        for (int m = 1; m < 64; m <<= 1) ss += __shfl_xor(ss, m);
        float sc = 1.0f / fmaxf(sqrtf(ss), 1e-12f);
        y0 *= sc; y1 *= sc; y2 *= sc; y3 *= sc;
        uint2 o;
        o.x = (u32)f2bf(y0) | ((u32)f2bf(y1) << 16);
        o.y = (u32)f2bf(y2) | ((u32)f2bf(y3) << 16);
        *(uint2*)(QN + ((long)b * 4 + 3) * DD + d) = o;
        return;
    }

    const int bh = blk >> 5, q = blk & 31;
    const int b = bh >> 2, h = bh & 3;
    const int w = tid >> 6, lane = tid & 63, g = lane >> 4, c = lane & 15;
    const long cb = (long)(bh * 32 + q);
    u16* WLp = (u16*)(pm + 32768);
    float* bv   = (float*)(pm + 49664);
    float* n2   = (float*)(pm + 49920);
    float* invn = (float*)(pm + 50176);
    float* ncl  = (float*)(pm + 50432);

    if (tid < 64) bv[tid] = BETA[((long)b * LL + 64 * q + tid) * HH + h];

    // ---- P0/P1: k-conv + KK^T in two d-half passes ----
    f32x4 aacc[4];
#pragma unroll
    for (int nt = 0; nt < 4; nt++) aacc[nt] = (f32x4){0.f, 0.f, 0.f, 0.f};

    const int dloc = tid & 127, th = tid >> 7;
#pragma unroll
    for (int pass = 0; pass < 2; pass++) {
        {
            const int dg = pass * 128 + dloc;
            float4 wt = ((const float4*)ck)[h * HD + dg];
            const u16* rp = R + ((long)b * LL + 64 * q) * 2048 + h * HD + dg;
            u16 arr[35];
            if (q == 0 && th == 0) {
                arr[0] = 0; arr[1] = 0; arr[2] = 0;
#pragma unroll
                for (int i = 3; i < 35; i++) arr[i] = rp[(long)(i - 3) * 2048];
            } else {
                const u16* rb = rp + (long)(32 * th - 3) * 2048;
#pragma unroll
                for (int i = 0; i < 35; i++) arr[i] = rb[(long)i * 2048];
            }
            u16 vals[8];
#pragma unroll
            for (int jj = 0; jj < 32; jj++) {
                int t = 32 * th + jj;
                float y = bf2f(arr[jj]) * wt.x + bf2f(arr[jj + 1]) * wt.y +
                          bf2f(arr[jj + 2]) * wt.z + bf2f(arr[jj + 3]) * wt.w;
                y = silu2_fast(y);
                u16 yb = f2bf(y);
                vals[t & 7] = yb;
                *(u16*)(pm + 32768 + t * 256 + ((((dloc >> 3) ^ (t & 7)) << 4) + (dloc & 7) * 2)) = yb;
                if ((t & 7) == 7)
                    *(uint4*)(pm + dg * 128 + (((t >> 3) ^ (dg & 7)) << 4)) = *(uint4*)vals;
            }
        }
        BAR_LGKM();
        {
            const int ra = 16 * w + c;
#pragma unroll
            for (int q8 = 0; q8 < 4; q8++) {
                short8 af = *(const short8*)(pm + 32768 + ra * 256 + (((4 * q8 + g) ^ (ra & 7)) << 4));
#pragma unroll
                for (int nt = 0; nt < 4; nt++) {
                    const int rb = 16 * nt + c;
                    short8 bf = *(const short8*)(pm + 32768 + rb * 256 + (((4 * q8 + g) ^ (rb & 7)) << 4));
                    aacc[nt] = __builtin_amdgcn_mfma_f32_16x16x32_bf16(af, bf, aacc[nt], 0, 0, 0);
                }
            }
        }
        BAR_LGKM();
    }

    // diag -> n2 -> ncl/invn
#pragma unroll
    for (int nt = 0; nt < 4; nt++)
        if (nt == w && (c >> 2) == g) n2[16 * w + c] = aacc[nt][c & 3];
    BAR_LGKM();
    if (tid < 64) {
        float nn = fmaxf(sqrtf(n2[tid]), 1e-12f);
        ncl[tid] = nn;
        invn[tid] = 1.0f / nn;
    }
    BAR_LGKM();

    // WL = A*b*invn_t*invn_s ; BKT out
    {
#pragma unroll
        for (int nt = 0; nt < 4; nt++)
#pragma unroll
            for (int r = 0; r < 4; r++) {
                int tt = 16 * w + 4 * g + r, s = 16 * nt + c;
                WLp[tt * 68 + s] = f2bf(aacc[nt][r] * bv[s] * invn[tt] * invn[s]);
            }
        for (int ii = tid; ii < 2048; ii += 256) {
            int dd = ii >> 3, bl = ii & 7;
            u16 vals[8];
            *(uint4*)vals = *(const uint4*)(pm + dd * 128 + bl * 16);
            int t0 = (bl ^ (dd & 7)) << 3;
#pragma unroll
            for (int j = 0; j < 8; j++)
                vals[j] = f2bf(bf2f(vals[j]) * bv[t0 + j] * invn[t0 + j]);
            *(uint4*)((char*)(BKT_g + cb * 16384) + dd * 128 + bl * 16) = *(uint4*)vals;
        }
    }
    BAR_LGKM();

    // ---- P2: register forward substitution ; LIbf = Linv[t][s]*invn[s] ----
    {
        const int col = 16 * w + c;
        const float sc_col = invn[col];
        float li[16];
#pragma unroll
        for (int u = 0; u < 16; u++) li[u] = (4 * u + g == col) ? 1.0f : 0.0f;
#pragma unroll
        for (int t = 1; t < 64; t++) {
            float acc = 0.f;
#pragma unroll
            for (int u = 0; u <= (t - 1) / 4; u++) {
                int s = 4 * u + g;
                if (s < t) acc += bf2f(WLp[t * 68 + s]) * li[u];
            }
            acc += __shfl_xor(acc, 16);
            acc += __shfl_xor(acc, 32);
            float val = ((t == col) ? 1.0f : 0.0f) - acc;
            if ((t & 3) == g) li[t >> 2] = val;
        }
#pragma unroll
        for (int u = 0; u < 16; u++) {
            int s = 4 * u + g;
            *(u16*)(pm + 41472 + s * 128 + ((((col >> 3) ^ (s & 7)) << 4) + (col & 7) * 2)) =
                f2bf(li[u] * sc_col);
        }
    }
    BAR_LGKM();

    // ---- P3: LK' = -Linv*K_norm, direct global stores ----
    {
        f32x4 lk[4][4];
#pragma unroll
        for (int i = 0; i < 4; i++)
#pragma unroll
            for (int j = 0; j < 4; j++) lk[i][j] = (f32x4){0.f, 0.f, 0.f, 0.f};
#pragma unroll
        for (int qs = 0; qs < 2; qs++) {
            short8 aL[4], bK[4];
#pragma unroll
            for (int mt = 0; mt < 4; mt++)
                aL[mt] = *(const short8*)(pm + 41472 + (16 * mt + c) * 128 +
                                          (((qs * 4 + g) ^ (c & 7)) << 4));
#pragma unroll
            for (int dn = 0; dn < 4; dn++)
                bK[dn] = *(const short8*)(pm + (64 * w + 16 * dn + c) * 128 +
                                          (((qs * 4 + g) ^ (c & 7)) << 4));
#pragma unroll
            for (int mt = 0; mt < 4; mt++)
#pragma unroll
                for (int dn = 0; dn < 4; dn++)
                    lk[mt][dn] = __builtin_amdgcn_mfma_f32_16x16x32_bf16(aL[mt], bK[dn], lk[mt][dn], 0, 0, 0);
        }
        char* lkg = (char*)(LK_g + cb * 16384);
#pragma unroll
        for (int mt = 0; mt < 4; mt++)
#pragma unroll
            for (int dn = 0; dn < 4; dn++)
#pragma unroll
                for (int r = 0; r < 4; r++) {
                    int t = 16 * mt + 4 * g + r;
                    int d = 64 * w + 16 * dn + c;
                    *(u16*)(lkg + t * 512 + ((((d >> 3) ^ (t & 7)) << 4) + (d & 7) * 2)) =
                        f2bf(-lk[mt][dn][r]);
                }
    }
    BAR_LGKM();   // KT reads done before VT overwrite

    // ---- P4: v-conv gather -> VT [d][t] scaled by ncl[t] (overwrites KT) ----
    {
        float4 wt = ((const float4*)cv)[h * HD + tid];
        const u16* rp = R + ((long)b * LL + 64 * q) * 2048 + 1024 + h * HD + tid;
#pragma unroll
        for (int hh = 0; hh < 2; hh++) {
            u16 arr[35];
            if (q == 0 && hh == 0) {
                arr[0] = 0; arr[1] = 0; arr[2] = 0;
#pragma unroll
                for (int i = 3; i < 35; i++) arr[i] = rp[(long)(i - 3) * 2048];
            } else {
                const u16* rb = rp + (long)(32 * hh - 3) * 2048;
#pragma unroll
                for (int i = 0; i < 35; i++) arr[i] = rb[(long)i * 2048];
            }
            u16 vals[8];
#pragma unroll
            for (int jj = 0; jj < 32; jj++) {
                int t = 32 * hh + jj;
                float y = bf2f(arr[jj]) * wt.x + bf2f(arr[jj + 1]) * wt.y +
                          bf2f(arr[jj + 2]) * wt.z + bf2f(arr[jj + 3]) * wt.w;
                y = silu2_fast(y) * ncl[t];
                vals[t & 7] = f2bf(y);
                if ((t & 7) == 7)
                    *(uint4*)(pm + tid * 128 + (((t >> 3) ^ (tid & 7)) << 4)) = *(uint4*)vals;
            }
        }
    }
    BAR_LGKM();

    // ---- P5: LV' = Linv*V, coalesced u32 plane stores ----
    {
        f32x4 lv[4][4];
#pragma unroll
        for (int i = 0; i < 4; i++)
#pragma unroll
            for (int j = 0; j < 4; j++) lv[i][j] = (f32x4){0.f, 0.f, 0.f, 0.f};
#pragma unroll
        for (int qs = 0; qs < 2; qs++) {
            short8 aL[4], bV[4];
#pragma unroll
            for (int mt = 0; mt < 4; mt++)
                aL[mt] = *(const short8*)(pm + 41472 + (16 * mt + c) * 128 +
                                          (((qs * 4 + g) ^ (c & 7)) << 4));
#pragma unroll
            for (int dn = 0; dn < 4; dn++)
                bV[dn] = *(const short8*)(pm + (64 * w + 16 * dn + c) * 128 +
                                          (((qs * 4 + g) ^ (c & 7)) << 4));
#pragma unroll
            for (int mt = 0; mt < 4; mt++)
#pragma unroll
                for (int dn = 0; dn < 4; dn++)
                    lv[mt][dn] = __builtin_amdgcn_mfma_f32_16x16x32_bf16(aL[mt], bV[dn], lv[mt][dn], 0, 0, 0);
        }
        u32* lvg = (u32*)LV_g + cb * 8192;
#pragma unroll
        for (int mt = 0; mt < 4; mt++)
#pragma unroll
            for (int dn = 0; dn < 4; dn++) {
                int iblk = 2 * w + (dn >> 1);
                int it = dn & 1;
                int base = iblk * 1024 + 64 * (2 * mt + it) + 16 * g + c;
                lvg[base]       = (u32)f2bf(lv[mt][dn][0]) | ((u32)f2bf(lv[mt][dn][1]) << 16);
                lvg[base + 512] = (u32)f2bf(lv[mt][dn][2]) | ((u32)f2bf(lv[mt][dn][3]) << 16);
            }
    }
}

// ---------------- chunked scan: 8 waves, 2 GEMMs/chunk, all-b128 LDS frags ----------------
__global__ __launch_bounds__(512, 1) void scan_chunked(
    const u16* __restrict__ LK_g, const u16* __restrict__ BKT_g,
    const u16* __restrict__ LV_g, const u16* __restrict__ QN,
    float* __restrict__ out, float* __restrict__ ORAW)
{
    __shared__ __align__(16) char smem[159744];
    const int blk = blockIdx.x;
    const int bh = blk & 31, iblk = blk >> 5;
    const int b = bh >> 2, h = bh & 3;
    const int row0 = iblk * 32;
    const int tid = threadIdx.x;
    const int w = tid >> 6, lane = tid & 63, g = lane >> 4, c = lane & 15;
    const int mt = w >> 1, it = w & 1;
    const int sw = (c & 7) << 4;

#define GLDS16(gp, lofs) __builtin_amdgcn_global_load_lds((const AS1 void*)(gp), \
        (AS3 void*)((AS3 char*)smem + (lofs)), 16, 0, 0)
#define GLDS4(gp, lofs) __builtin_amdgcn_global_load_lds((const AS1 void*)(gp), \
        (AS3 void*)((AS3 char*)smem + (lofs)), 4, 0, 0)
#define STAGE_LK(qq, bi) { const char* gp = (const char*)(LK_g + (long)(bh * 32 + (qq)) * 16384); \
    _Pragma("unroll") for (int i_ = 0; i_ < 4; i_++) GLDS16(gp + i_ * 8192 + tid * 16, (bi) * 32768 + i_ * 8192 + tid * 16); }
#define STAGE_BKT(qq, bi) { const char* gp = (const char*)(BKT_g + (long)(bh * 32 + (qq)) * 16384); \
    _Pragma("unroll") for (int i_ = 0; i_ < 4; i_++) GLDS16(gp + i_ * 8192 + tid * 16, 65536 + (bi) * 32768 + i_ * 8192 + tid * 16); }
#define STAGE_LV(qq, bi) { const char* gp = (const char*)LV_g + (long)(bh * 32 + (qq)) * 32768 + iblk * 4096; \
    GLDS4(gp + tid * 4, 131072 + (bi) * 4096 + tid * 4); \
    GLDS4(gp + 2048 + tid * 4, 131072 + (bi) * 4096 + 2048 + tid * 4); }

    f32x4 S[2][2];
#pragma unroll
    for (int si = 0; si < 2; si++)
#pragma unroll
        for (int sj = 0; sj < 2; sj++) S[si][sj] = (f32x4){0.f, 0.f, 0.f, 0.f};

    STAGE_LK(0, 0); STAGE_BKT(0, 0); STAGE_LV(0, 0);

    for (int q = 0; q < 32; ++q) {
        const int cur = q & 1;
        if (q < 31) {
            STAGE_LK(q + 1, cur ^ 1); STAGE_BKT(q + 1, cur ^ 1); STAGE_LV(q + 1, cur ^ 1);
            asm volatile("s_waitcnt vmcnt(10)" ::: "memory");
        } else {
            asm volatile("s_waitcnt vmcnt(0)" ::: "memory");
        }
        __builtin_amdgcn_s_barrier();
        __builtin_amdgcn_sched_barrier(0);

        const char* lkb = smem + cur * 32768;
        const char* bkb = smem + 65536 + cur * 32768;
        const char* lvb = smem + 131072 + cur * 4096;

        // ---- W = LK' * S^T + LV' ----
        u32 l0 = *(const u32*)(lvb + tid * 4);
        u32 l1 = *(const u32*)(lvb + 2048 + tid * 4);
        f32x4 w0, w1;
        w0[0] = bf2f((u16)(l0 & 0xffff)); w0[1] = bf2f((u16)(l0 >> 16));
        w0[2] = bf2f((u16)(l1 & 0xffff)); w0[3] = bf2f((u16)(l1 >> 16));
        w1 = (f32x4){0.f, 0.f, 0.f, 0.f};
        if (q > 0) {
            const int arow = (16 * mt + c) * 512;
            const int brow = (16 * it + c) * 512;
            __builtin_amdgcn_s_setprio(1);
#pragma unroll
            for (int q8 = 0; q8 < 8; q8++) {
                short8 av = *(const short8*)(lkb + arow + (((q8 * 4 + g) << 4) ^ sw));
                short8 bv8 = *(const short8*)(smem + 143360 + brow + (((q8 * 4 + g) << 4) ^ sw));
                if (q8 & 1) w1 = __builtin_amdgcn_mfma_f32_16x16x32_bf16(av, bv8, w1, 0, 0, 0);
                else        w0 = __builtin_amdgcn_mfma_f32_16x16x32_bf16(av, bv8, w0, 0, 0, 0);
            }
            __builtin_amdgcn_s_setprio(0);
#pragma unroll
            for (int r = 0; r < 4; r++) w0[r] += w1[r];
        }

        // ---- all-gather W into WLDS [32 i][64 t] swz ----
        {
            char* ub = smem + 139264 + (16 * it + c) * 128;
#pragma unroll
            for (int r = 0; r < 4; r++) {
                int t = 16 * mt + 4 * g + r;
                *(u16*)(ub + ((((t >> 3) << 4) ^ sw) + (t & 7) * 2)) = f2bf(w0[r]);
            }
        }
        asm volatile("s_waitcnt lgkmcnt(0)" ::: "memory");
        __builtin_amdgcn_s_barrier();
        __builtin_amdgcn_sched_barrier(0);

        // ---- S += W^T * (bK) ----
        __builtin_amdgcn_s_setprio(1);
#pragma unroll
        for (int Qp = 0; Qp < 2; Qp++) {
            const int tof = ((Qp * 4 + g) << 4) ^ sw;
            short8 a0 = *(const short8*)(smem + 139264 + c * 128 + tof);
            short8 a1 = *(const short8*)(smem + 139264 + (16 + c) * 128 + tof);
            short8 b0 = *(const short8*)(bkb + (32 * w + c) * 128 + tof);
            short8 b1 = *(const short8*)(bkb + (32 * w + 16 + c) * 128 + tof);
            S[0][0] = __builtin_amdgcn_mfma_f32_16x16x32_bf16(a0, b0, S[0][0], 0, 0, 0);
            S[0][1] = __builtin_amdgcn_mfma_f32_16x16x32_bf16(a0, b1, S[0][1], 0, 0, 0);
            S[1][0] = __builtin_amdgcn_mfma_f32_16x16x32_bf16(a1, b0, S[1][0], 0, 0, 0);
            S[1][1] = __builtin_amdgcn_mfma_f32_16x16x32_bf16(a1, b1, S[1][1], 0, 0, 0);
        }
        __builtin_amdgcn_s_setprio(0);

        // ---- S -> TS for next chunk ----
        if (q < 31) {
#pragma unroll
            for (int si = 0; si < 2; si++)
#pragma unroll
                for (int sj = 0; sj < 2; sj++)
#pragma unroll
                    for (int r = 0; r < 4; r++) {
                        int i = 16 * si + 4 * g + r;
                        *(u16*)(smem + 143360 + i * 512 +
                                ((((4 * w + 2 * sj + (c >> 3)) << 4) ^ ((i & 7) << 4)) + (c & 7) * 2)) =
                            f2bf(S[si][sj][r]);
                    }
        }
        asm volatile("s_waitcnt lgkmcnt(0)" ::: "memory");
        __builtin_amdgcn_s_barrier();
        __builtin_amdgcn_sched_barrier(0);
    }

    // ---- epilogue ----
    float op[2][4];
#pragma unroll
    for (int si = 0; si < 2; si++)
#pragma unroll
        for (int r = 0; r < 4; r++) op[si][r] = 0.f;
#pragma unroll
    for (int sj = 0; sj < 2; sj++) {
        const float qv = bf2f(QN[((long)b * 4 + 3) * DD + h * HD + 32 * w + 16 * sj + c]);
#pragma unroll
        for (int si = 0; si < 2; si++)
#pragma unroll
            for (int r = 0; r < 4; r++) op[si][r] += S[si][sj][r] * qv;
    }
#pragma unroll
    for (int si = 0; si < 2; si++)
#pragma unroll
        for (int r = 0; r < 4; r++) {
            float v = op[si][r];
            v += __shfl_xor(v, 1); v += __shfl_xor(v, 2);
            v += __shfl_xor(v, 4); v += __shfl_xor(v, 8);
            op[si][r] = v;
        }
    float* red = (float*)smem;
    if (c == 0) {
#pragma unroll
        for (int si = 0; si < 2; si++)
#pragma unroll
            for (int r = 0; r < 4; r++) red[w * 32 + 16 * si + 4 * g + r] = op[si][r];
    }
    __syncthreads();
    if (tid < 32) {
        float o = 0.f;
#pragma unroll
        for (int ww = 0; ww < 8; ww++) o += red[ww * 32 + tid];
        ORAW[(long)b * DD + h * HD + row0 + tid] = o;
    }
#pragma unroll
    for (int si = 0; si < 2; si++)
#pragma unroll
        for (int sj = 0; sj < 2; sj++)
#pragma unroll
            for (int r = 0; r < 4; r++)
                out[8192 + ((long)(bh * 256 + row0 + 16 * si + 4 * g + r)) * 256
                    + 32 * w + 16 * sj + c] = S[si][sj][r];
#undef GLDS16
#undef GLDS4
#undef STAGE_LK
#undef STAGE_BKT
#undef STAGE_LV
}

// ---------------- tail: rmsnorm + out projection fused ----------------
__global__ __launch_bounds__(256) void tail_kernel(const float* __restrict__ ORAW,
                                                   const float* __restrict__ rms_w,
                                                   const float* __restrict__ Wout,
                                                   float* __restrict__ out) {
    const int b = blockIdx.x >> 8;
    const int n = (blockIdx.x & 255) * 4 + (threadIdx.x >> 6);
    const int lane = threadIdx.x & 63;
    const int t = threadIdx.x;

    float4 v = *(const float4*)(ORAW + (long)b * DD + t * 4);
    float ss = v.x * v.x + v.y * v.y + v.z * v.z + v.w * v.w;
#pragma unroll
    for (int m = 1; m < 64; m <<= 1) ss += __shfl_xor(ss, m);
    __shared__ float wsum[4];
    if ((t & 63) == 0) wsum[t >> 6] = ss;
    __syncthreads();
    float tot = wsum[0] + wsum[1] + wsum[2] + wsum[3];
    float sc = rsqrtf(tot / (float)DD + 1e-5f);

    const float* orow = ORAW + (long)b * DD + lane * 16;
    const float* grow = rms_w + lane * 16;
    const float* wrow = Wout + (long)n * DD + lane * 16;
    float s = 0.f;
#pragma unroll
    for (int u = 0; u < 4; u++) {
        float4 a = *(const float4*)(orow + u * 4);
        float4 gw = *(const float4*)(grow + u * 4);
        float4 ww = *(const float4*)(wrow + u * 4);
        s += a.x * sc * gw.x * ww.x + a.y * sc * gw.y * ww.y +
             a.z * sc * gw.z * ww.z + a.w * sc * gw.w * ww.w;
    }
#pragma unroll
    for (int m = 1; m < 64; m <<= 1) s += __shfl_xor(s, m);
    if (lane == 0) out[(long)b * DD + n] = s;
}

extern "C" void kernel_launch(void* const* d_in, const int* in_sizes, int n_in,
                              void* d_out, int out_size, void* d_ws, size_t ws_size,
                              hipStream_t stream) {
    const float* x     = (const float*)d_in[0];
    const float* Wq    = (const float*)d_in[1];
    const float* Wk    = (const float*)d_in[2];
    const float* Wv    = (const float*)d_in[3];
    const float* cq    = (const float*)d_in[4];
    const float* ck    = (const float*)d_in[5];
    const float* cv    = (const float*)d_in[6];
    const float* Wbeta = (const float*)d_in[7];
    const float* rms_w = (const float*)d_in[8];
    const float* Wout  = (const float*)d_in[9];
    float* out = (float*)d_out;

    char* ws = (char*)d_ws;
    u16* XB     = (u16*)(ws + 0);           // 32 MB (dead after gemm)
    u16* BKT_g  = (u16*)(ws + 0);           // overlays XB (prep runs after gemm)
    u16* WKVB   = (u16*)(ws + 33554432);    // 4 MB [Wk;Wv]
    u16* R      = (u16*)(ws + 37748736);    // 64 MB [16384][2048] (alive through prep)
    u16* LK_g   = (u16*)(ws + 104857600);   // 32 MB
    u16* LV_g   = (u16*)(ws + 138412032);   // 32 MB
    float* BETA = (float*)(ws + 171966464); // 256 KB
    u16* RQ     = (u16*)(ws + 172228608);   // 64 KB
    u16* QN     = (u16*)(ws + 172294144);   // 64 KB
    float* ORAW = (float*)(ws + 172359680); // 32 KB

    front_kernel<<<9472, 256, 0, stream>>>(x, Wk, Wv, Wbeta, Wq, XB, WKVB, BETA, RQ);
    gemm_8ph<<<512, 512, 0, stream>>>(XB, WKVB, R);
    prep_fused<<<1032, 256, 0, stream>>>(R, ck, cv, cq, RQ, BETA, LK_g, BKT_g, LV_g, QN);
    scan_chunked<<<256, 512, 0, stream>>>(LK_g, BKT_g, LV_g, QN, out, ORAW);
    tail_kernel<<<2048, 256, 0, stream>>>(ORAW, rms_w, Wout, out);
}